// Round 31
// baseline (94.441 us; speedup 1.0000x reference)
//
#include <hip/hip_runtime.h>
#include <hip/hip_bf16.h>

#define BB 2
#define TT 2048
#define DMM 1024
#define HH 16
#define HDD 64

typedef __attribute__((ext_vector_type(8))) short bf16x8;
typedef __attribute__((ext_vector_type(4))) short short4v;
typedef __attribute__((ext_vector_type(4))) float f32x4;

static __device__ __forceinline__ short f2bf(float f) {
    __hip_bfloat16 h = __float2bfloat16(f);
    return *reinterpret_cast<short*>(&h);
}

static __device__ __forceinline__ float ex2(float x) {
    return __builtin_amdgcn_exp2f(x);    // v_exp_f32: D = 2^S0
}

static __device__ __forceinline__ void gl_lds16(const void* g, void* l) {
    __builtin_amdgcn_global_load_lds(
        (const __attribute__((address_space(1))) void*)g,
        (__attribute__((address_space(3))) void*)l, 16, 0, 0);
}

// ---- fused prep v2 (vectorized): y<3 = W_eff (+LoRA) cast bf16; y==3 = hidden f32->bf16 ----
__global__ void prep_all(const float* __restrict__ hidden, short* __restrict__ Xbf,
                         const float* __restrict__ Wq, const float* __restrict__ Aq, const float* __restrict__ Bq,
                         const float* __restrict__ Wk,
                         const float* __restrict__ Wv, const float* __restrict__ Av, const float* __restrict__ Bv,
                         short* __restrict__ Wqe, short* __restrict__ Wke, short* __restrict__ Wve) {
    const int mode = blockIdx.y;
    const int tid0 = blockIdx.x * 256 + threadIdx.x;
    if (mode == 3) {                                 // hidden: 4 strided float4s (16 elems)
#pragma unroll
        for (int kk = 0; kk < 4; ++kk) {
            int i = tid0 + kk * 262144;              // 1024*256 = 262144 float4s per pass
            float4 v = reinterpret_cast<const float4*>(hidden)[i];
            short4v o;
            o[0] = f2bf(v.x); o[1] = f2bf(v.y); o[2] = f2bf(v.z); o[3] = f2bf(v.w);
            reinterpret_cast<short4v*>(Xbf)[i] = o;
        }
        return;
    }
    const float* W = (mode == 0) ? Wq : (mode == 1) ? Wk : Wv;
    const float* A = (mode == 0) ? Aq : Av;
    const float* Bm = (mode == 0) ? Bq : Bv;
    short* outp = (mode == 0) ? Wqe : (mode == 1) ? Wke : Wve;
    const int idx4 = tid0 * 4;                       // 4 consecutive elems, same row n
    const int n = idx4 >> 10, k = idx4 & 1023;
    float4 w = *reinterpret_cast<const float4*>(W + idx4);
    if (mode != 1) {
        float4 s = {0.f, 0.f, 0.f, 0.f};
#pragma unroll
        for (int r = 0; r < 8; ++r) {
            float br = Bm[n * 8 + r];
            float4 a = *reinterpret_cast<const float4*>(A + r * 1024 + k);
            s.x += br * a.x; s.y += br * a.y; s.z += br * a.z; s.w += br * a.w;
        }
        w.x += 2.0f * s.x; w.y += 2.0f * s.y; w.z += 2.0f * s.z; w.w += 2.0f * s.w;
    }
    short4v o;
    o[0] = f2bf(w.x); o[1] = f2bf(w.y); o[2] = f2bf(w.z); o[3] = f2bf(w.w);
    *reinterpret_cast<short4v*>(outp + idx4) = o;
}

// ---- projection GEMM v6: FUSED QKV, 64M x 128N x BK=64 (R27/R28 proven) ----
__global__ __launch_bounds__(256) void proj_fused(
        const short* __restrict__ Xbf,
        const short* __restrict__ Wqe, const short* __restrict__ Wke, const short* __restrict__ Wve,
        const float* __restrict__ bq, const float* __restrict__ bk, const float* __restrict__ bv,
        short* __restrict__ Qb, short* __restrict__ Kb, short* __restrict__ Vtb) {
    __shared__ __align__(16) char XS[8192];          // X tile 64x64 bf16
    __shared__ __align__(16) char WS[3][16384];      // Wq/Wk/Wv tiles 128x64 bf16

    const int tid = threadIdx.x;
    const int wave = tid >> 6, lane = tid & 63;
    const int l15 = lane & 15, l4 = lane >> 4;
    const int bx = blockIdx.x, by = blockIdx.y;
    const int wx = 2 * (bx & 3) + (by & 1);          // W panel 0..7
    const int wy = (bx >> 2) * 32 + (by >> 1);       // X panel 0..63
    const int m0 = wy * 64, n0 = wx * 128;
    const int wm = (wave >> 1) * 32, wn = (wave & 1) * 64;

    // staging: 128B rows, 8 chunks of 16B; instr covers 8 rows x 8 chunks.
    const int lr8 = lane >> 3;                       // row within 8-row group
    const int srcc = ((lane & 7) ^ lr8) * 8;         // pre-swizzled source chunk (shorts)

    f32x4 aq[4][2] = {}, ak[4][2] = {}, av[2][4] = {};

    for (int k0 = 0; k0 < 1024; k0 += 64) {
        __syncthreads();                             // prev compute done; LDS free
#pragma unroll
        for (int i = 0; i < 2; ++i)                  // X rows [wave*16, +16)
            gl_lds16(Xbf + (m0 + wave * 16 + i * 8 + lr8) * 1024 + k0 + srcc,
                     XS + wave * 2048 + i * 1024);
#pragma unroll
        for (int i = 0; i < 4; ++i) {                // W rows [wave*32, +32) x 3
            gl_lds16(Wqe + (n0 + wave * 32 + i * 8 + lr8) * 1024 + k0 + srcc,
                     WS[0] + wave * 4096 + i * 1024);
            gl_lds16(Wke + (n0 + wave * 32 + i * 8 + lr8) * 1024 + k0 + srcc,
                     WS[1] + wave * 4096 + i * 1024);
            gl_lds16(Wve + (n0 + wave * 32 + i * 8 + lr8) * 1024 + k0 + srcc,
                     WS[2] + wave * 4096 + i * 1024);
        }
        __syncthreads();                             // staged tile ready

#pragma unroll
        for (int kk = 0; kk < 2; ++kk) {
            const int colb = kk * 64 + l4 * 16;
            bf16x8 xf[2];
#pragma unroll
            for (int x = 0; x < 2; ++x) {
                int r = wm + x * 16 + l15;
                xf[x] = *reinterpret_cast<const bf16x8*>(XS + ((r * 128 + colb) ^ ((r & 7) << 4)));
            }
            {
                bf16x8 wf[4];
#pragma unroll
                for (int w = 0; w < 4; ++w) {
                    int r = wn + w * 16 + l15;
                    wf[w] = *reinterpret_cast<const bf16x8*>(WS[0] + ((r * 128 + colb) ^ ((r & 7) << 4)));
                }
#pragma unroll
                for (int w = 0; w < 4; ++w)
#pragma unroll
                    for (int x = 0; x < 2; ++x)
                        aq[w][x] = __builtin_amdgcn_mfma_f32_16x16x32_bf16(wf[w], xf[x], aq[w][x], 0, 0, 0);
            }
            {
                bf16x8 wf[4];
#pragma unroll
                for (int w = 0; w < 4; ++w) {
                    int r = wn + w * 16 + l15;
                    wf[w] = *reinterpret_cast<const bf16x8*>(WS[1] + ((r * 128 + colb) ^ ((r & 7) << 4)));
                }
#pragma unroll
                for (int w = 0; w < 4; ++w)
#pragma unroll
                    for (int x = 0; x < 2; ++x)
                        ak[w][x] = __builtin_amdgcn_mfma_f32_16x16x32_bf16(wf[w], xf[x], ak[w][x], 0, 0, 0);
            }
            {
                bf16x8 wf[4];
#pragma unroll
                for (int w = 0; w < 4; ++w) {
                    int r = wn + w * 16 + l15;
                    wf[w] = *reinterpret_cast<const bf16x8*>(WS[2] + ((r * 128 + colb) ^ ((r & 7) << 4)));
                }
#pragma unroll
                for (int x = 0; x < 2; ++x)
#pragma unroll
                    for (int w = 0; w < 4; ++w)
                        av[x][w] = __builtin_amdgcn_mfma_f32_16x16x32_bf16(xf[x], wf[w], av[x][w], 0, 0, 0);
            }
        }
    }

    // ---- epilogue Q (C^T, scaled) ----
#pragma unroll
    for (int w = 0; w < 4; ++w) {
        int gnb = n0 + wn + w * 16 + l4 * 4;         // 4 consecutive features
        int hh = gnb >> 6, d = gnb & 63;
        float4 bv4 = *reinterpret_cast<const float4*>(bq + gnb);
#pragma unroll
        for (int x = 0; x < 2; ++x) {
            int gm = m0 + wm + x * 16 + l15;
            int bb = gm >> 11, t = gm & 2047;
            short4v o;
            o[0] = f2bf((aq[w][x][0] + bv4.x) * 0.18033688f);
            o[1] = f2bf((aq[w][x][1] + bv4.y) * 0.18033688f);
            o[2] = f2bf((aq[w][x][2] + bv4.z) * 0.18033688f);
            o[3] = f2bf((aq[w][x][3] + bv4.w) * 0.18033688f);
            *reinterpret_cast<short4v*>(Qb + ((bb * 16 + hh) * 2048 + t) * 64 + d) = o;
        }
    }
    // ---- epilogue K (C^T) ----
#pragma unroll
    for (int w = 0; w < 4; ++w) {
        int gnb = n0 + wn + w * 16 + l4 * 4;
        int hh = gnb >> 6, d = gnb & 63;
        float4 bv4 = *reinterpret_cast<const float4*>(bk + gnb);
#pragma unroll
        for (int x = 0; x < 2; ++x) {
            int gm = m0 + wm + x * 16 + l15;
            int bb = gm >> 11, t = gm & 2047;
            short4v o;
            o[0] = f2bf(ak[w][x][0] + bv4.x);
            o[1] = f2bf(ak[w][x][1] + bv4.y);
            o[2] = f2bf(ak[w][x][2] + bv4.z);
            o[3] = f2bf(ak[w][x][3] + bv4.w);
            *reinterpret_cast<short4v*>(Kb + ((bb * 16 + hh) * 2048 + t) * 64 + d) = o;
        }
    }
    // ---- epilogue V (C, V^T [d][t] with half-swap) ----
#pragma unroll
    for (int x = 0; x < 2; ++x) {
        int gmb = m0 + wm + x * 16 + l4 * 4;         // 4 consecutive tokens
        int bb = gmb >> 11, t = gmb & 2047;
#pragma unroll
        for (int w = 0; w < 4; ++w) {
            int gn = n0 + wn + w * 16 + l15;
            int hh = gn >> 6, d = gn & 63;
            int tx = ((gn >> 3) & 1) << 2;           // half-swap for attn V read
            float bvs = bv[gn];
            short4v o;
            o[0] = f2bf(av[x][w][0] + bvs);
            o[1] = f2bf(av[x][w][1] + bvs);
            o[2] = f2bf(av[x][w][2] + bvs);
            o[3] = f2bf(av[x][w][3] + bvs);
            *reinterpret_cast<short4v*>(Vtb + ((bb * 16 + hh) * 64 + d) * 2048 + (t ^ tx)) = o;
        }
    }
}

// ---- flash attention v12: counted-vmcnt pipeline, unroll-by-4 (R22 proven) ----

#define STAGE(BUF, T) do {                                                           \
    const int _kv = (T) << 5;                                                        \
    gl_lds16(Kp + (_kv + krow) * 64 + kswz, MEM + (BUF) * 4096 + wv * 1024);         \
    gl_lds16(Vp + lane * 2048 + _kv + wv * 8, MEM + 16384 + (BUF) * 4096 + wv * 1024);\
} while (0)

#define SLICEJOB(QF0, QF1, OO, M, L, QBASE) do {                                     \
    f32x4 ss = {};                                                                   \
    ss = __builtin_amdgcn_mfma_f32_16x16x32_bf16(kf0, QF0, ss, 0, 0, 0);             \
    ss = __builtin_amdgcn_mfma_f32_16x16x32_bf16(kf1, QF1, ss, 0, 0, 0);             \
    float pr[4];                                                                     \
    if (kvs + 15 > (QBASE)) {                                                        \
        _Pragma("unroll")                                                            \
        for (int r = 0; r < 4; ++r) {                                                \
            float v = ss[r] + mv[r];                                                 \
            if (kvs + l4*4 + r > (QBASE) + l15) v = -1e30f;                          \
            pr[r] = v;                                                               \
        }                                                                            \
    } else {                                                                         \
        _Pragma("unroll")                                                            \
        for (int r = 0; r < 4; ++r) pr[r] = ss[r] + mv[r];                           \
    }                                                                                \
    float tl = fmaxf(fmaxf(pr[0], pr[1]), fmaxf(pr[2], pr[3]));                      \
    if (!__all(tl - (M) <= 11.5415603f)) {                                           \
        float tm = tl;                                                               \
        tm = fmaxf(tm, __shfl_xor(tm, 16));                                          \
        tm = fmaxf(tm, __shfl_xor(tm, 32));                                          \
        float mn = fmaxf((M), tm);                                                   \
        float al = ex2((M) - mn);                                                    \
        M = mn; L *= al;                                                             \
        _Pragma("unroll")                                                            \
        for (int dt = 0; dt < 4; ++dt)                                               \
            _Pragma("unroll")                                                        \
            for (int r = 0; r < 4; ++r) OO[dt][r] *= al;                             \
    }                                                                                \
    _Pragma("unroll")                                                                \
    for (int r = 0; r < 4; ++r) pr[r] = ex2(pr[r] - (M));                            \
    L += (pr[0] + pr[1]) + (pr[2] + pr[3]);                                          \
    short4v pa;                                                                      \
    _Pragma("unroll")                                                                \
    for (int r = 0; r < 4; ++r) pa[r] = f2bf(pr[r]);                                 \
    _Pragma("unroll")                                                                \
    for (int dt = 0; dt < 4; ++dt)                                                   \
        OO[dt] = __builtin_amdgcn_mfma_f32_16x16x16bf16_1k(vf[dt], pa, OO[dt], 0, 0, 0); \
} while (0)

#define AITER(BUF, T) do {                                                           \
    if ((T) + 2 < NT) {                                                              \
        STAGE((((BUF) + 2) & 3), (T) + 2);                                           \
        asm volatile("s_waitcnt vmcnt(4)" ::: "memory");                             \
    } else if ((T) + 1 < NT) {                                                       \
        asm volatile("s_waitcnt vmcnt(2)" ::: "memory");                             \
    } else {                                                                         \
        asm volatile("s_waitcnt vmcnt(0)" ::: "memory");                             \
    }                                                                                \
    asm volatile("s_barrier" ::: "memory");                                          \
    if ((T) < nkA) {                                                                 \
        const char* Kcur = MEM + (BUF) * 4096;                                       \
        const char* Vcur = MEM + 16384 + (BUF) * 4096;                               \
        bf16x8 kf0 = *reinterpret_cast<const bf16x8*>(Kcur + kb0);                   \
        bf16x8 kf1 = *reinterpret_cast<const bf16x8*>(Kcur + (kb0 ^ 64));            \
        short4v vf[4];                                                               \
        _Pragma("unroll")                                                            \
        for (int dt = 0; dt < 4; ++dt)                                               \
            vf[dt] = *reinterpret_cast<const short4v*>(Vcur + vb0 + dt * 256);       \
        const int kvs = ((T) << 5) + 16 * s;                                         \
        float4 mv = *reinterpret_cast<const float4*>(mlds + kvs + l4 * 4);           \
        SLICEJOB(qfA0, qfA1, OA, MA, LA, qbaseA);                                    \
        if ((T) < nkB) SLICEJOB(qfB0, qfB1, OB, MB, LB, qbaseB);                     \
    }                                                                                \
} while (0)

// LDS (bytes): K 4-buf [4][4096] @0 | V 4-buf [4][4096] @16384 | mask 8192 @32768 = 40960
// merge regions reuse @0 after the stream loop (20480 B, over dead K/V buffers)
__global__ __launch_bounds__(256, 4) void attn(
        const short* __restrict__ Qb, const short* __restrict__ Kb,
        const short* __restrict__ Vt, const float* __restrict__ amask,
        float* __restrict__ outp) {
    __shared__ __align__(16) char MEM[40960];

    const int tid = threadIdx.x, wv = tid >> 6, lane = tid & 63;
    const int l15 = lane & 15, l4 = lane >> 4;
    // XCD-chunked + bit-mixed j: robust CU-level balance under round-robin fill
    const int xcd = blockIdx.x & 7;
    const int k   = blockIdx.x >> 3;                 // 0..127 within XCD
    const int j   = ((k >> 5) << 3) | ((k & 3) << 1) | ((k >> 4) & 1);  // 0..31
    const int bh  = xcd * 4 + ((k >> 2) & 3);        // 4 bh per XCD (L2 locality)
    const int p  = wv & 1;                           // pair in block
    const int s  = wv >> 1;                          // key-slice
    const int i  = 2 * j + p;                        // pair index 0..63
    const int b = bh >> 4, h = bh & 15;

    const short* Qp = Qb + bh * TT * HDD;
    const short* Kp = Kb + bh * TT * HDD;
    const short* Vp = Vt + bh * HDD * TT;
    const float* mp = amask + b * TT;
    float* mlds = (float*)(MEM + 32768);

    const int qbaseA = (127 - i) << 4;
    const int qbaseB = i << 4;
    const int nkA = ((qbaseA + 15 - 16 * s) >> 5) + 1;   // slice-aware causal bounds
    const int nkB = ((qbaseB + 15 - 16 * s) >> 5) + 1;   // (0 when slice fully masked)
    const int NT = ((127 - 2 * j) * 16 + 47) >> 5;       // block stream extent (>= 33)

    // staging lane geometry: K rows [wv*8,+8) pre-swizzled; V chunk wv, d=lane
    const int krow = wv * 8 + (lane >> 3);
    const int kswz = ((lane & 7) ^ (lane >> 3)) * 8;     // shorts

    // LDS read offsets (bytes)
    const int kb0 = (16 * s + l15) * 128 + ((l4 ^ (l15 & 7)) << 4);
    const int vb0 = (2 * s + (l4 >> 1)) * 1024 + l15 * 16 + (((l4 & 1) ^ (l15 >> 3)) << 3);

    // prologue: mask -> LDS (whole row for this b), scaled to log2 domain
    {
        int mi8 = tid * 8;
        float4 a = *reinterpret_cast<const float4*>(mp + mi8);
        float4 c = *reinterpret_cast<const float4*>(mp + mi8 + 4);
        a.x *= 1.44269504f; a.y *= 1.44269504f; a.z *= 1.44269504f; a.w *= 1.44269504f;
        c.x *= 1.44269504f; c.y *= 1.44269504f; c.z *= 1.44269504f; c.w *= 1.44269504f;
        *reinterpret_cast<float4*>(mlds + mi8) = a;
        *reinterpret_cast<float4*>(mlds + mi8 + 4) = c;
    }

    bf16x8 qfA0 = *reinterpret_cast<const bf16x8*>(Qp + (qbaseA + l15) * 64 + l4 * 8);
    bf16x8 qfA1 = *reinterpret_cast<const bf16x8*>(Qp + (qbaseA + l15) * 64 + 32 + l4 * 8);
    bf16x8 qfB0 = *reinterpret_cast<const bf16x8*>(Qp + (qbaseB + l15) * 64 + l4 * 8);
    bf16x8 qfB1 = *reinterpret_cast<const bf16x8*>(Qp + (qbaseB + l15) * 64 + 32 + l4 * 8);

    f32x4 OA[4] = {}, OB[4] = {};
    float MA = -1e30f, LA = 0.f, MB = -1e30f, LB = 0.f;

    STAGE(0, 0);                                     // tiles 0,1 in flight
    STAGE(1, 1);                                     // (NT >= 33, both exist)
    asm volatile("s_waitcnt lgkmcnt(0)" ::: "memory");   // mask writes retired

    int t = 0;
    for (; t + 4 <= NT; t += 4) {                    // unrolled: static buffer bases
        AITER(0, t);
        AITER(1, t + 1);
        AITER(2, t + 2);
        AITER(3, t + 3);
    }
    for (; t < NT; ++t) AITER((t & 3), t);           // tail (0..3 iters)

    asm volatile("s_barrier" ::: "memory");          // loop reads done before merge reuse

    // reduce l across l4 groups (per slice)
    LA += __shfl_xor(LA, 16); LA += __shfl_xor(LA, 32);
    LB += __shfl_xor(LB, 16); LB += __shfl_xor(LB, 32);

    // disjoint-key merge: slice-1 posts, slice-0 merges + writes
    float* mg = (float*)MEM + p * 2560 + lane * 40;  // 160B/lane, 16B-aligned chunks
    if (s) {
#pragma unroll
        for (int dt = 0; dt < 4; ++dt) *reinterpret_cast<f32x4*>(mg + dt * 4) = OA[dt];
        mg[16] = MA; mg[17] = LA;
#pragma unroll
        for (int dt = 0; dt < 4; ++dt) *reinterpret_cast<f32x4*>(mg + 20 + dt * 4) = OB[dt];
        mg[36] = MB; mg[37] = LB;
    }
    __syncthreads();
    if (!s) {
        {
            float m1 = mg[16], l1 = mg[17];
            float ms = fmaxf(MA, m1);
            float e0 = ex2(MA - ms), e1 = ex2(m1 - ms);
            float inv = 1.0f / (LA * e0 + l1 * e1);
            int tA = qbaseA + l15;
#pragma unroll
            for (int dt = 0; dt < 4; ++dt) {
                f32x4 o1 = *reinterpret_cast<const f32x4*>(mg + dt * 4);
                float4 o;
                o.x = (OA[dt][0] * e0 + o1[0] * e1) * inv;
                o.y = (OA[dt][1] * e0 + o1[1] * e1) * inv;
                o.z = (OA[dt][2] * e0 + o1[2] * e1) * inv;
                o.w = (OA[dt][3] * e0 + o1[3] * e1) * inv;
                *reinterpret_cast<float4*>(outp + (b * 2048 + tA) * 1024 + h * 64 + dt * 16 + l4 * 4) = o;
            }
        }
        {
            float m1 = mg[36], l1 = mg[37];
            float ms = fmaxf(MB, m1);
            float e0 = ex2(MB - ms), e1 = ex2(m1 - ms);
            float inv = 1.0f / (LB * e0 + l1 * e1);
            int tB = qbaseB + l15;
#pragma unroll
            for (int dt = 0; dt < 4; ++dt) {
                f32x4 o1 = *reinterpret_cast<const f32x4*>(mg + 20 + dt * 4);
                float4 o;
                o.x = (OB[dt][0] * e0 + o1[0] * e1) * inv;
                o.y = (OB[dt][1] * e0 + o1[1] * e1) * inv;
                o.z = (OB[dt][2] * e0 + o1[2] * e1) * inv;
                o.w = (OB[dt][3] * e0 + o1[3] * e1) * inv;
                *reinterpret_cast<float4*>(outp + (b * 2048 + tB) * 1024 + h * 64 + dt * 16 + l4 * 4) = o;
            }
        }
    }
}

extern "C" void kernel_launch(void* const* d_in, const int* in_sizes, int n_in,
                              void* d_out, int out_size, void* d_ws, size_t ws_size,
                              hipStream_t stream) {
    const float* hidden = (const float*)d_in[0];
    const float* amask  = (const float*)d_in[1];
    const float* Wq = (const float*)d_in[2];
    const float* bq = (const float*)d_in[3];
    const float* Aq = (const float*)d_in[4];
    const float* Bq = (const float*)d_in[5];
    const float* Wk = (const float*)d_in[6];
    const float* bk = (const float*)d_in[7];
    const float* Wv = (const float*)d_in[8];
    const float* bv = (const float*)d_in[9];
    const float* Av = (const float*)d_in[10];
    const float* Bv = (const float*)d_in[11];
    float* outp = (float*)d_out;

    char* ws = (char*)d_ws;
    short* Xbf = (short*)(ws);                 // 8 MB  [4096][1024] bf16
    short* Wqe = (short*)(ws + (8 << 20));     // 2 MB
    short* Wke = (short*)(ws + (10 << 20));    // 2 MB
    short* Wve = (short*)(ws + (12 << 20));    // 2 MB
    short* Qb  = (short*)(ws + (14 << 20));    // 8 MB  [b][h][t][d] (pre-scaled by 0.125*log2e)
    short* Kb  = (short*)(ws + (22 << 20));    // 8 MB  [b][h][t][d]
    short* Vtb = (short*)(ws + (30 << 20));    // 8 MB  [b][h][d][t] (half-swapped)

    prep_all<<<dim3(1024, 4), 256, 0, stream>>>(hidden, Xbf, Wq, Aq, Bq, Wk, Wv, Av, Bv, Wqe, Wke, Wve);
    proj_fused<<<dim3(8, 64), 256, 0, stream>>>(Xbf, Wqe, Wke, Wve, bq, bk, bv, Qb, Kb, Vtb);
    attn<<<1024, 256, 0, stream>>>(Qb, Kb, Vtb, amask, outp);
}

// Round 32
// 93.659 us; speedup vs baseline: 1.0083x; 1.0083x over previous
//
#include <hip/hip_runtime.h>
#include <hip/hip_bf16.h>

#define BB 2
#define TT 2048
#define DMM 1024
#define HH 16
#define HDD 64

typedef __attribute__((ext_vector_type(8))) short bf16x8;
typedef __attribute__((ext_vector_type(4))) short short4v;
typedef __attribute__((ext_vector_type(4))) float f32x4;

static __device__ __forceinline__ short f2bf(float f) {
    __hip_bfloat16 h = __float2bfloat16(f);
    return *reinterpret_cast<short*>(&h);
}

static __device__ __forceinline__ float ex2(float x) {
    return __builtin_amdgcn_exp2f(x);    // v_exp_f32: D = 2^S0
}

static __device__ __forceinline__ void gl_lds16(const void* g, void* l) {
    __builtin_amdgcn_global_load_lds(
        (const __attribute__((address_space(1))) void*)g,
        (__attribute__((address_space(3))) void*)l, 16, 0, 0);
}

// ---- fused prep v2 (vectorized): y<3 = W_eff (+LoRA) cast bf16; y==3 = hidden f32->bf16 ----
__global__ void prep_all(const float* __restrict__ hidden, short* __restrict__ Xbf,
                         const float* __restrict__ Wq, const float* __restrict__ Aq, const float* __restrict__ Bq,
                         const float* __restrict__ Wk,
                         const float* __restrict__ Wv, const float* __restrict__ Av, const float* __restrict__ Bv,
                         short* __restrict__ Wqe, short* __restrict__ Wke, short* __restrict__ Wve) {
    const int mode = blockIdx.y;
    const int tid0 = blockIdx.x * 256 + threadIdx.x;
    if (mode == 3) {                                 // hidden: 4 strided float4s (16 elems)
#pragma unroll
        for (int kk = 0; kk < 4; ++kk) {
            int i = tid0 + kk * 262144;              // 1024*256 = 262144 float4s per pass
            float4 v = reinterpret_cast<const float4*>(hidden)[i];
            short4v o;
            o[0] = f2bf(v.x); o[1] = f2bf(v.y); o[2] = f2bf(v.z); o[3] = f2bf(v.w);
            reinterpret_cast<short4v*>(Xbf)[i] = o;
        }
        return;
    }
    const float* W = (mode == 0) ? Wq : (mode == 1) ? Wk : Wv;
    const float* A = (mode == 0) ? Aq : Av;
    const float* Bm = (mode == 0) ? Bq : Bv;
    short* outp = (mode == 0) ? Wqe : (mode == 1) ? Wke : Wve;
    const int idx4 = tid0 * 4;                       // 4 consecutive elems, same row n
    const int n = idx4 >> 10, k = idx4 & 1023;
    float4 w = *reinterpret_cast<const float4*>(W + idx4);
    if (mode != 1) {
        float4 s = {0.f, 0.f, 0.f, 0.f};
#pragma unroll
        for (int r = 0; r < 8; ++r) {
            float br = Bm[n * 8 + r];
            float4 a = *reinterpret_cast<const float4*>(A + r * 1024 + k);
            s.x += br * a.x; s.y += br * a.y; s.z += br * a.z; s.w += br * a.w;
        }
        w.x += 2.0f * s.x; w.y += 2.0f * s.y; w.z += 2.0f * s.z; w.w += 2.0f * s.w;
    }
    short4v o;
    o[0] = f2bf(w.x); o[1] = f2bf(w.y); o[2] = f2bf(w.z); o[3] = f2bf(w.w);
    *reinterpret_cast<short4v*>(outp + idx4) = o;
}

// ---- projection GEMM v6: FUSED QKV, 64M x 128N x BK=64 (R27/R28 proven) ----
__global__ __launch_bounds__(256) void proj_fused(
        const short* __restrict__ Xbf,
        const short* __restrict__ Wqe, const short* __restrict__ Wke, const short* __restrict__ Wve,
        const float* __restrict__ bq, const float* __restrict__ bk, const float* __restrict__ bv,
        short* __restrict__ Qb, short* __restrict__ Kb, short* __restrict__ Vtb) {
    __shared__ __align__(16) char XS[8192];          // X tile 64x64 bf16
    __shared__ __align__(16) char WS[3][16384];      // Wq/Wk/Wv tiles 128x64 bf16

    const int tid = threadIdx.x;
    const int wave = tid >> 6, lane = tid & 63;
    const int l15 = lane & 15, l4 = lane >> 4;
    const int bx = blockIdx.x, by = blockIdx.y;
    const int wx = 2 * (bx & 3) + (by & 1);          // W panel 0..7
    const int wy = (bx >> 2) * 32 + (by >> 1);       // X panel 0..63
    const int m0 = wy * 64, n0 = wx * 128;
    const int wm = (wave >> 1) * 32, wn = (wave & 1) * 64;

    // staging: 128B rows, 8 chunks of 16B; instr covers 8 rows x 8 chunks.
    const int lr8 = lane >> 3;                       // row within 8-row group
    const int srcc = ((lane & 7) ^ lr8) * 8;         // pre-swizzled source chunk (shorts)

    f32x4 aq[4][2] = {}, ak[4][2] = {}, av[2][4] = {};

    for (int k0 = 0; k0 < 1024; k0 += 64) {
        __syncthreads();                             // prev compute done; LDS free
#pragma unroll
        for (int i = 0; i < 2; ++i)                  // X rows [wave*16, +16)
            gl_lds16(Xbf + (m0 + wave * 16 + i * 8 + lr8) * 1024 + k0 + srcc,
                     XS + wave * 2048 + i * 1024);
#pragma unroll
        for (int i = 0; i < 4; ++i) {                // W rows [wave*32, +32) x 3
            gl_lds16(Wqe + (n0 + wave * 32 + i * 8 + lr8) * 1024 + k0 + srcc,
                     WS[0] + wave * 4096 + i * 1024);
            gl_lds16(Wke + (n0 + wave * 32 + i * 8 + lr8) * 1024 + k0 + srcc,
                     WS[1] + wave * 4096 + i * 1024);
            gl_lds16(Wve + (n0 + wave * 32 + i * 8 + lr8) * 1024 + k0 + srcc,
                     WS[2] + wave * 4096 + i * 1024);
        }
        __syncthreads();                             // staged tile ready

#pragma unroll
        for (int kk = 0; kk < 2; ++kk) {
            const int colb = kk * 64 + l4 * 16;
            bf16x8 xf[2];
#pragma unroll
            for (int x = 0; x < 2; ++x) {
                int r = wm + x * 16 + l15;
                xf[x] = *reinterpret_cast<const bf16x8*>(XS + ((r * 128 + colb) ^ ((r & 7) << 4)));
            }
            {
                bf16x8 wf[4];
#pragma unroll
                for (int w = 0; w < 4; ++w) {
                    int r = wn + w * 16 + l15;
                    wf[w] = *reinterpret_cast<const bf16x8*>(WS[0] + ((r * 128 + colb) ^ ((r & 7) << 4)));
                }
#pragma unroll
                for (int w = 0; w < 4; ++w)
#pragma unroll
                    for (int x = 0; x < 2; ++x)
                        aq[w][x] = __builtin_amdgcn_mfma_f32_16x16x32_bf16(wf[w], xf[x], aq[w][x], 0, 0, 0);
            }
            {
                bf16x8 wf[4];
#pragma unroll
                for (int w = 0; w < 4; ++w) {
                    int r = wn + w * 16 + l15;
                    wf[w] = *reinterpret_cast<const bf16x8*>(WS[1] + ((r * 128 + colb) ^ ((r & 7) << 4)));
                }
#pragma unroll
                for (int w = 0; w < 4; ++w)
#pragma unroll
                    for (int x = 0; x < 2; ++x)
                        ak[w][x] = __builtin_amdgcn_mfma_f32_16x16x32_bf16(wf[w], xf[x], ak[w][x], 0, 0, 0);
            }
            {
                bf16x8 wf[4];
#pragma unroll
                for (int w = 0; w < 4; ++w) {
                    int r = wn + w * 16 + l15;
                    wf[w] = *reinterpret_cast<const bf16x8*>(WS[2] + ((r * 128 + colb) ^ ((r & 7) << 4)));
                }
#pragma unroll
                for (int x = 0; x < 2; ++x)
#pragma unroll
                    for (int w = 0; w < 4; ++w)
                        av[x][w] = __builtin_amdgcn_mfma_f32_16x16x32_bf16(xf[x], wf[w], av[x][w], 0, 0, 0);
            }
        }
    }

    // ---- epilogue Q (C^T, scaled) ----
#pragma unroll
    for (int w = 0; w < 4; ++w) {
        int gnb = n0 + wn + w * 16 + l4 * 4;         // 4 consecutive features
        int hh = gnb >> 6, d = gnb & 63;
        float4 bv4 = *reinterpret_cast<const float4*>(bq + gnb);
#pragma unroll
        for (int x = 0; x < 2; ++x) {
            int gm = m0 + wm + x * 16 + l15;
            int bb = gm >> 11, t = gm & 2047;
            short4v o;
            o[0] = f2bf((aq[w][x][0] + bv4.x) * 0.18033688f);
            o[1] = f2bf((aq[w][x][1] + bv4.y) * 0.18033688f);
            o[2] = f2bf((aq[w][x][2] + bv4.z) * 0.18033688f);
            o[3] = f2bf((aq[w][x][3] + bv4.w) * 0.18033688f);
            *reinterpret_cast<short4v*>(Qb + ((bb * 16 + hh) * 2048 + t) * 64 + d) = o;
        }
    }
    // ---- epilogue K (C^T) ----
#pragma unroll
    for (int w = 0; w < 4; ++w) {
        int gnb = n0 + wn + w * 16 + l4 * 4;
        int hh = gnb >> 6, d = gnb & 63;
        float4 bv4 = *reinterpret_cast<const float4*>(bk + gnb);
#pragma unroll
        for (int x = 0; x < 2; ++x) {
            int gm = m0 + wm + x * 16 + l15;
            int bb = gm >> 11, t = gm & 2047;
            short4v o;
            o[0] = f2bf(ak[w][x][0] + bv4.x);
            o[1] = f2bf(ak[w][x][1] + bv4.y);
            o[2] = f2bf(ak[w][x][2] + bv4.z);
            o[3] = f2bf(ak[w][x][3] + bv4.w);
            *reinterpret_cast<short4v*>(Kb + ((bb * 16 + hh) * 2048 + t) * 64 + d) = o;
        }
    }
    // ---- epilogue V (C, V^T [d][t] with half-swap) ----
#pragma unroll
    for (int x = 0; x < 2; ++x) {
        int gmb = m0 + wm + x * 16 + l4 * 4;         // 4 consecutive tokens
        int bb = gmb >> 11, t = gmb & 2047;
#pragma unroll
        for (int w = 0; w < 4; ++w) {
            int gn = n0 + wn + w * 16 + l15;
            int hh = gn >> 6, d = gn & 63;
            int tx = ((gn >> 3) & 1) << 2;           // half-swap for attn V read
            float bvs = bv[gn];
            short4v o;
            o[0] = f2bf(av[x][w][0] + bvs);
            o[1] = f2bf(av[x][w][1] + bvs);
            o[2] = f2bf(av[x][w][2] + bvs);
            o[3] = f2bf(av[x][w][3] + bvs);
            *reinterpret_cast<short4v*>(Vtb + ((bb * 16 + hh) * 64 + d) * 2048 + (t ^ tx)) = o;
        }
    }
}

// ---- flash attention v15: 3-ring + post-compute STAGE -> 32KB LDS, 5 blocks/CU ----
// Iteration t: vmcnt -> barrier -> compute(t) -> STAGE(t+2). A wave issuing
// STAGE(t+2) passed barrier(t), so ALL waves finished compute(t-1); the ring slot
// being overwritten ((t+2)%3 == (t-1)%3) is provably dead. 2 loads/wave/tile ->
// steady vmcnt(2), final iter vmcnt(0). LDS 40960 -> 32768 = 5 blocks/CU (+25% waves).

#define STAGE(BUF, T) do {                                                           \
    const int _kv = (T) << 5;                                                        \
    gl_lds16(Kp + (_kv + krow) * 64 + kswz, MEM + (BUF) * 4096 + wv * 1024);         \
    gl_lds16(Vp + lane * 2048 + _kv + wv * 8, MEM + 12288 + (BUF) * 4096 + wv * 1024);\
} while (0)

#define SLICEJOB(QF0, QF1, OO, M, L, QBASE) do {                                     \
    f32x4 ss = {};                                                                   \
    ss = __builtin_amdgcn_mfma_f32_16x16x32_bf16(kf0, QF0, ss, 0, 0, 0);             \
    ss = __builtin_amdgcn_mfma_f32_16x16x32_bf16(kf1, QF1, ss, 0, 0, 0);             \
    float pr[4];                                                                     \
    if (kvs + 15 > (QBASE)) {                                                        \
        _Pragma("unroll")                                                            \
        for (int r = 0; r < 4; ++r) {                                                \
            float v = ss[r] + mv[r];                                                 \
            if (kvs + l4*4 + r > (QBASE) + l15) v = -1e30f;                          \
            pr[r] = v;                                                               \
        }                                                                            \
    } else {                                                                         \
        _Pragma("unroll")                                                            \
        for (int r = 0; r < 4; ++r) pr[r] = ss[r] + mv[r];                           \
    }                                                                                \
    float tl = fmaxf(fmaxf(pr[0], pr[1]), fmaxf(pr[2], pr[3]));                      \
    if (!__all(tl - (M) <= 11.5415603f)) {                                           \
        float tm = tl;                                                               \
        tm = fmaxf(tm, __shfl_xor(tm, 16));                                          \
        tm = fmaxf(tm, __shfl_xor(tm, 32));                                          \
        float mn = fmaxf((M), tm);                                                   \
        float al = ex2((M) - mn);                                                    \
        M = mn; L *= al;                                                             \
        _Pragma("unroll")                                                            \
        for (int dt = 0; dt < 4; ++dt)                                               \
            _Pragma("unroll")                                                        \
            for (int r = 0; r < 4; ++r) OO[dt][r] *= al;                             \
    }                                                                                \
    _Pragma("unroll")                                                                \
    for (int r = 0; r < 4; ++r) pr[r] = ex2(pr[r] - (M));                            \
    L += (pr[0] + pr[1]) + (pr[2] + pr[3]);                                          \
    short4v pa;                                                                      \
    _Pragma("unroll")                                                                \
    for (int r = 0; r < 4; ++r) pa[r] = f2bf(pr[r]);                                 \
    _Pragma("unroll")                                                                \
    for (int dt = 0; dt < 4; ++dt)                                                   \
        OO[dt] = __builtin_amdgcn_mfma_f32_16x16x16bf16_1k(vf[dt], pa, OO[dt], 0, 0, 0); \
} while (0)

#define AITER(BUF, T) do {                                                           \
    if ((T) + 1 < NT) {                                                              \
        asm volatile("s_waitcnt vmcnt(2)" ::: "memory");                             \
    } else {                                                                         \
        asm volatile("s_waitcnt vmcnt(0)" ::: "memory");                             \
    }                                                                                \
    asm volatile("s_barrier" ::: "memory");                                          \
    if ((T) < nkA) {                                                                 \
        const char* Kcur = MEM + (BUF) * 4096;                                       \
        const char* Vcur = MEM + 12288 + (BUF) * 4096;                               \
        bf16x8 kf0 = *reinterpret_cast<const bf16x8*>(Kcur + kb0);                   \
        bf16x8 kf1 = *reinterpret_cast<const bf16x8*>(Kcur + (kb0 ^ 64));            \
        short4v vf[4];                                                               \
        _Pragma("unroll")                                                            \
        for (int dt = 0; dt < 4; ++dt)                                               \
            vf[dt] = *reinterpret_cast<const short4v*>(Vcur + vb0 + dt * 256);       \
        const int kvs = ((T) << 5) + 16 * s;                                         \
        float4 mv = *reinterpret_cast<const float4*>(mlds + kvs + l4 * 4);           \
        SLICEJOB(qfA0, qfA1, OA, MA, LA, qbaseA);                                    \
        if ((T) < nkB) SLICEJOB(qfB0, qfB1, OB, MB, LB, qbaseB);                     \
    }                                                                                \
    if ((T) + 2 < NT) STAGE((((BUF) + 2) % 3), (T) + 2);                             \
} while (0)

// LDS (bytes): K 3-ring [3][4096] @0 | V 3-ring [3][4096] @12288 | mask 8192 @24576 = 32768
// merge regions reuse @0 after the stream loop (20480 B, over dead K/V buffers)
__global__ __launch_bounds__(256, 4) void attn(
        const short* __restrict__ Qb, const short* __restrict__ Kb,
        const short* __restrict__ Vt, const float* __restrict__ amask,
        float* __restrict__ outp) {
    __shared__ __align__(16) char MEM[32768];

    const int tid = threadIdx.x, wv = tid >> 6, lane = tid & 63;
    const int l15 = lane & 15, l4 = lane >> 4;
    // XCD-chunked + bit-mixed j: robust CU-level balance under round-robin fill
    const int xcd = blockIdx.x & 7;
    const int k   = blockIdx.x >> 3;                 // 0..127 within XCD
    const int j   = ((k >> 5) << 3) | ((k & 3) << 1) | ((k >> 4) & 1);  // 0..31
    const int bh  = xcd * 4 + ((k >> 2) & 3);        // 4 bh per XCD (L2 locality)
    const int p  = wv & 1;                           // pair in block
    const int s  = wv >> 1;                          // key-slice
    const int i  = 2 * j + p;                        // pair index 0..63
    const int b = bh >> 4, h = bh & 15;

    const short* Qp = Qb + bh * TT * HDD;
    const short* Kp = Kb + bh * TT * HDD;
    const short* Vp = Vt + bh * HDD * TT;
    const float* mp = amask + b * TT;
    float* mlds = (float*)(MEM + 24576);

    const int qbaseA = (127 - i) << 4;
    const int qbaseB = i << 4;
    const int nkA = ((qbaseA + 15 - 16 * s) >> 5) + 1;   // slice-aware causal bounds
    const int nkB = ((qbaseB + 15 - 16 * s) >> 5) + 1;   // (0 when slice fully masked)
    const int NT = ((127 - 2 * j) * 16 + 47) >> 5;       // block stream extent (>= 33)

    // staging lane geometry: K rows [wv*8,+8) pre-swizzled; V chunk wv, d=lane
    const int krow = wv * 8 + (lane >> 3);
    const int kswz = ((lane & 7) ^ (lane >> 3)) * 8;     // shorts

    // LDS read offsets (bytes)
    const int kb0 = (16 * s + l15) * 128 + ((l4 ^ (l15 & 7)) << 4);
    const int vb0 = (2 * s + (l4 >> 1)) * 1024 + l15 * 16 + (((l4 & 1) ^ (l15 >> 3)) << 3);

    // prologue: mask -> LDS (whole row for this b), scaled to log2 domain
    {
        int mi8 = tid * 8;
        float4 a = *reinterpret_cast<const float4*>(mp + mi8);
        float4 c = *reinterpret_cast<const float4*>(mp + mi8 + 4);
        a.x *= 1.44269504f; a.y *= 1.44269504f; a.z *= 1.44269504f; a.w *= 1.44269504f;
        c.x *= 1.44269504f; c.y *= 1.44269504f; c.z *= 1.44269504f; c.w *= 1.44269504f;
        *reinterpret_cast<float4*>(mlds + mi8) = a;
        *reinterpret_cast<float4*>(mlds + mi8 + 4) = c;
    }

    bf16x8 qfA0 = *reinterpret_cast<const bf16x8*>(Qp + (qbaseA + l15) * 64 + l4 * 8);
    bf16x8 qfA1 = *reinterpret_cast<const bf16x8*>(Qp + (qbaseA + l15) * 64 + 32 + l4 * 8);
    bf16x8 qfB0 = *reinterpret_cast<const bf16x8*>(Qp + (qbaseB + l15) * 64 + l4 * 8);
    bf16x8 qfB1 = *reinterpret_cast<const bf16x8*>(Qp + (qbaseB + l15) * 64 + 32 + l4 * 8);

    f32x4 OA[4] = {}, OB[4] = {};
    float MA = -1e30f, LA = 0.f, MB = -1e30f, LB = 0.f;

    STAGE(0, 0);                                     // tiles 0,1 in flight
    STAGE(1, 1);                                     // (NT >= 33, both exist)
    asm volatile("s_waitcnt lgkmcnt(0)" ::: "memory");   // mask writes retired

    int t = 0;
    for (; t + 3 <= NT; t += 3) {                    // unrolled: static ring bases
        AITER(0, t);
        AITER(1, t + 1);
        AITER(2, t + 2);
    }
    for (; t < NT; ++t) AITER((t % 3), t);           // tail (0..2 iters, phase-consistent)

    asm volatile("s_barrier" ::: "memory");          // loop reads done before merge reuse

    // reduce l across l4 groups (per slice)
    LA += __shfl_xor(LA, 16); LA += __shfl_xor(LA, 32);
    LB += __shfl_xor(LB, 16); LB += __shfl_xor(LB, 32);

    // disjoint-key merge: slice-1 posts, slice-0 merges + writes
    float* mg = (float*)MEM + p * 2560 + lane * 40;  // 160B/lane, 16B-aligned chunks
    if (s) {
#pragma unroll
        for (int dt = 0; dt < 4; ++dt) *reinterpret_cast<f32x4*>(mg + dt * 4) = OA[dt];
        mg[16] = MA; mg[17] = LA;
#pragma unroll
        for (int dt = 0; dt < 4; ++dt) *reinterpret_cast<f32x4*>(mg + 20 + dt * 4) = OB[dt];
        mg[36] = MB; mg[37] = LB;
    }
    __syncthreads();
    if (!s) {
        {
            float m1 = mg[16], l1 = mg[17];
            float ms = fmaxf(MA, m1);
            float e0 = ex2(MA - ms), e1 = ex2(m1 - ms);
            float inv = 1.0f / (LA * e0 + l1 * e1);
            int tA = qbaseA + l15;
#pragma unroll
            for (int dt = 0; dt < 4; ++dt) {
                f32x4 o1 = *reinterpret_cast<const f32x4*>(mg + dt * 4);
                float4 o;
                o.x = (OA[dt][0] * e0 + o1[0] * e1) * inv;
                o.y = (OA[dt][1] * e0 + o1[1] * e1) * inv;
                o.z = (OA[dt][2] * e0 + o1[2] * e1) * inv;
                o.w = (OA[dt][3] * e0 + o1[3] * e1) * inv;
                *reinterpret_cast<float4*>(outp + (b * 2048 + tA) * 1024 + h * 64 + dt * 16 + l4 * 4) = o;
            }
        }
        {
            float m1 = mg[36], l1 = mg[37];
            float ms = fmaxf(MB, m1);
            float e0 = ex2(MB - ms), e1 = ex2(m1 - ms);
            float inv = 1.0f / (LB * e0 + l1 * e1);
            int tB = qbaseB + l15;
#pragma unroll
            for (int dt = 0; dt < 4; ++dt) {
                f32x4 o1 = *reinterpret_cast<const f32x4*>(mg + 20 + dt * 4);
                float4 o;
                o.x = (OB[dt][0] * e0 + o1[0] * e1) * inv;
                o.y = (OB[dt][1] * e0 + o1[1] * e1) * inv;
                o.z = (OB[dt][2] * e0 + o1[2] * e1) * inv;
                o.w = (OB[dt][3] * e0 + o1[3] * e1) * inv;
                *reinterpret_cast<float4*>(outp + (b * 2048 + tB) * 1024 + h * 64 + dt * 16 + l4 * 4) = o;
            }
        }
    }
}

extern "C" void kernel_launch(void* const* d_in, const int* in_sizes, int n_in,
                              void* d_out, int out_size, void* d_ws, size_t ws_size,
                              hipStream_t stream) {
    const float* hidden = (const float*)d_in[0];
    const float* amask  = (const float*)d_in[1];
    const float* Wq = (const float*)d_in[2];
    const float* bq = (const float*)d_in[3];
    const float* Aq = (const float*)d_in[4];
    const float* Bq = (const float*)d_in[5];
    const float* Wk = (const float*)d_in[6];
    const float* bk = (const float*)d_in[7];
    const float* Wv = (const float*)d_in[8];
    const float* bv = (const float*)d_in[9];
    const float* Av = (const float*)d_in[10];
    const float* Bv = (const float*)d_in[11];
    float* outp = (float*)d_out;

    char* ws = (char*)d_ws;
    short* Xbf = (short*)(ws);                 // 8 MB  [4096][1024] bf16
    short* Wqe = (short*)(ws + (8 << 20));     // 2 MB
    short* Wke = (short*)(ws + (10 << 20));    // 2 MB
    short* Wve = (short*)(ws + (12 << 20));    // 2 MB
    short* Qb  = (short*)(ws + (14 << 20));    // 8 MB  [b][h][t][d] (pre-scaled by 0.125*log2e)
    short* Kb  = (short*)(ws + (22 << 20));    // 8 MB  [b][h][t][d]
    short* Vtb = (short*)(ws + (30 << 20));    // 8 MB  [b][h][d][t] (half-swapped)

    prep_all<<<dim3(1024, 4), 256, 0, stream>>>(hidden, Xbf, Wq, Aq, Bq, Wk, Wv, Av, Bv, Wqe, Wke, Wve);
    proj_fused<<<dim3(8, 64), 256, 0, stream>>>(Xbf, Wqe, Wke, Wve, bq, bk, bv, Qb, Kb, Vtb);
    attn<<<1024, 256, 0, stream>>>(Qb, Kb, Vtb, amask, outp);
}